// Round 11
// baseline (148.004 us; speedup 1.0000x reference)
//
#include <hip/hip_runtime.h>
#include <hip/hip_bf16.h>

#define B_ 4
#define I_ 512
#define J_ 512
#define C_ 512
#define P_ 128
#define H_ 4
#define D_ 32
#define HD_ 128
#define EPS_ 1e-5f
#define INF_ 1.0e9f
#define QSCALE_ 0.17677669529663689f

#define PB_BLOCKS 2048            // pair: persistent blocks (4 waves each)
#define PB_WAVES (PB_BLOCKS * 4)  // 8192 waves
#define PB_TILES 65536            // B*I*J/16
#define PB_ITERS (PB_TILES / PB_WAVES)  // 8 tiles per wave

typedef __attribute__((ext_vector_type(8))) short bf16x8;
typedef __attribute__((ext_vector_type(4))) short s16x4;
typedef __attribute__((ext_vector_type(4))) float f32x4;

__device__ __forceinline__ short f2bf(float f) {
    return __bfloat16_as_short(__float2bfloat16(f));
}
__device__ __forceinline__ float bf2f(short s) {
    return __uint_as_float(((unsigned)(unsigned short)s) << 16);
}

// ---------------------------------------------------------------------------
// K1: small prep.
//   block 0:         fold pair weights (MFMA B-frags) + AB[16]
//   blocks 1..128:   transpose {wq,wk,wv,wg} -> wT bf16 (q-scale folded)
//   blocks 129..160: transpose wo -> woT[col][k] bf16
// grid: 161 blocks, 256 threads
// ---------------------------------------------------------------------------
__global__ __launch_bounds__(256) void k_prep(
    const float* __restrict__ lng, const float* __restrict__ lnb,
    const float* __restrict__ wpb, const float* __restrict__ wpg,
    const float* __restrict__ wq, const float* __restrict__ wk,
    const float* __restrict__ wv, const float* __restrict__ wg,
    const float* __restrict__ wo,
    short* __restrict__ gwfB, float* __restrict__ AB,
    short* __restrict__ wT, short* __restrict__ woT)
{
    const int bx  = blockIdx.x;
    const int tid = threadIdx.x;

    if (bx == 0) {
        __shared__ float sAB[P_ * 16];
        const int s = tid >> 6, lane = tid & 63;
        const int c = lane >> 4, n = lane & 15;
#pragma unroll
        for (int e = 0; e < 8; e++) {
            const int p = s * 32 + c * 8 + e;
            const float w = (n < 4) ? wpb[p * 4 + n]
                          : (n < 8) ? wpg[p * 4 + (n - 4)] : 0.0f;
            gwfB[(s * 64 + lane) * 8 + e] = f2bf(lng[p] * w);
        }
        if (tid < P_) {
            const int p = tid;
            const float g = lng[p], b = lnb[p];
#pragma unroll
            for (int h = 0; h < 4; h++) {
                const float wb = wpb[p * 4 + h], wgv = wpg[p * 4 + h];
                sAB[p * 16 + h]      = g * wb;
                sAB[p * 16 + 4 + h]  = g * wgv;
                sAB[p * 16 + 8 + h]  = b * wb;
                sAB[p * 16 + 12 + h] = b * wgv;
            }
        }
        __syncthreads();
        if (tid < 16) {
            float a = 0.0f;
            for (int p = 0; p < P_; p++) a += sAB[p * 16 + tid];
            AB[tid] = a;
        }
    } else if (bx < 129) {
        const int bx2 = bx - 1;             // 0..127
        const int m   = bx2 >> 5, sub = bx2 & 31;
        const float* W = (m == 0) ? wq : (m == 1) ? wk : (m == 2) ? wv : wg;
        const float scale = (m == 0) ? QSCALE_ : 1.0f;
        const int col = sub * 4 + (tid >> 6);
        const int c0  = (tid & 63) * 8;
        bf16x8 pk;
#pragma unroll
        for (int u = 0; u < 8; u++)
            pk[u] = f2bf(W[(size_t)(c0 + u) * HD_ + col] * scale);
        *(bf16x8*)(wT + m * 65536 + col * 512 + c0) = pk;
    } else {
        const int bx3 = bx - 129;           // 0..31
        const int col = bx3 * 16 + (tid & 15);
        const int k0  = (tid >> 4) * 8;
        bf16x8 pk;
#pragma unroll
        for (int u = 0; u < 8; u++)
            pk[u] = f2bf(wo[(size_t)(k0 + u) * C_ + col]);
        *(bf16x8*)(woT + col * HD_ + k0) = pk;
    }
}

// ---------------------------------------------------------------------------
// pair helpers (NT loads; wave-private swizzled LDS bounce)
// ---------------------------------------------------------------------------
__device__ __forceinline__ void pb_load_coal(
    f32x4 (&ld)[8], float& pm, int tile,
    const float* __restrict__ pair, const int* __restrict__ pmask,
    int lane, int r)
{
    const float* tb = pair + (size_t)tile * 2048 + lane * 4;
#pragma unroll
    for (int s = 0; s < 8; s++)
        ld[s] = __builtin_nontemporal_load((const f32x4*)(tb + s * 256));
    pm = (float)pmask[tile * 16 + r];
}

__device__ __forceinline__ void pb_stage(
    char* __restrict__ my, const f32x4 (&ld)[8], int lane)
{
    const int half = lane >> 5;
    const int wb   = (lane & 31) * 16;
#pragma unroll
    for (int s = 0; s < 8; s++) {
        const int row = s * 2 + half;
        *(f32x4*)(my + row * 512 + (wb ^ ((row & 7) << 4))) = ld[s];
    }
}

__device__ __forceinline__ void pb_compute(
    const char* __restrict__ my, float pm, int tile,
    const bf16x8 (&bfrag)[4], float Al, float Ag, float Bl, float Bg,
    short* __restrict__ bias_bf, int lane, int r, int c)
{
    const char* rowb = my + r * 512;
    const int swz = (r & 7) << 4;
    f32x4 xa[4], xb[4];
#pragma unroll
    for (int ss = 0; ss < 4; ss++) {
        const int b0 = c * 32 + ss * 128;
        xa[ss] = *(const f32x4*)(rowb + ((b0)      ^ swz));
        xb[ss] = *(const f32x4*)(rowb + ((b0 + 16) ^ swz));
    }

    f32x4 acc = {0.0f, 0.0f, 0.0f, 0.0f};
    float sum = 0.0f, sq = 0.0f;
#pragma unroll
    for (int s = 0; s < 4; s++) {
        const float e0 = xa[s].x, e1 = xa[s].y, e2 = xa[s].z, e3 = xa[s].w;
        const float e4 = xb[s].x, e5 = xb[s].y, e6 = xb[s].z, e7 = xb[s].w;
        sum += e0 + e1 + e2 + e3 + e4 + e5 + e6 + e7;
        sq = fmaf(e0, e0, sq); sq = fmaf(e1, e1, sq);
        sq = fmaf(e2, e2, sq); sq = fmaf(e3, e3, sq);
        sq = fmaf(e4, e4, sq); sq = fmaf(e5, e5, sq);
        sq = fmaf(e6, e6, sq); sq = fmaf(e7, e7, sq);
        bf16x8 afrag;
        afrag[0] = f2bf(e0); afrag[1] = f2bf(e1);
        afrag[2] = f2bf(e2); afrag[3] = f2bf(e3);
        afrag[4] = f2bf(e4); afrag[5] = f2bf(e5);
        afrag[6] = f2bf(e6); afrag[7] = f2bf(e7);
        acc = __builtin_amdgcn_mfma_f32_16x16x32_bf16(afrag, bfrag[s], acc, 0, 0, 0);
    }

    sum += __shfl_xor(sum, 16); sum += __shfl_xor(sum, 32);
    sq  += __shfl_xor(sq, 16);  sq  += __shfl_xor(sq, 32);
    const float mean = sum * (1.0f / P_);
    const float rstd = rsqrtf(sq * (1.0f / P_) - mean * mean + EPS_);
    const float mr   = mean * rstd;
    const float mb   = INF_ * (pm - 1.0f);

    const int base = tile * 16;
    const int j0 = base & (J_ - 1);
    const int i  = (base >> 9) & (I_ - 1);
    const int b  = base >> 18;
    const int n4 = r & 3;
    short* obase = bias_bf + (((size_t)(b * H_ + n4) * I_ + i) << 9) + j0;

    s16x4 pk;
#pragma unroll
    for (int reg = 0; reg < 4; reg++) {
        const int rr = c * 4 + reg;
        const float rstd_r = __shfl(rstd, rr);
        const float mr_r   = __shfl(mr, rr);
        const float mb_r   = __shfl(mb, rr);
        const float Sg     = __shfl(acc[reg], lane + 4);
        const float left = fmaf(rstd_r, acc[reg], fmaf(-mr_r, Al, Bl));
        const float glog = fmaf(rstd_r, Sg,       fmaf(-mr_r, Ag, Bg));
        pk[reg] = f2bf(left * (1.0f / (1.0f + __expf(-glog))) + mb_r);
    }
    if (r < 4) *(s16x4*)(obase + c * 4) = pk;   // 4 contiguous j -> one 8B store
}

// ---------------------------------------------------------------------------
// K2: fused kernel.
//   blocks 0..127:   projections with inline LayerNorm (m==0 writes ni)
//   blocks 128..+PB: persistent pair-bias stream (NT, LDS bounce), bf16 bias
// grid: 128 + PB_BLOCKS, block: 256
// ---------------------------------------------------------------------------
__global__ __launch_bounds__(256, 4) void k_fused(
    const float* __restrict__ pair, const int* __restrict__ pmask,
    const short* __restrict__ gwfB, const float* __restrict__ AB,
    short* __restrict__ bias_bf,
    const float* __restrict__ node_i, const float* __restrict__ node_j,
    const float* __restrict__ g_i, const float* __restrict__ b_i,
    const float* __restrict__ g_j, const float* __restrict__ b_j,
    const short* __restrict__ wT, const float* __restrict__ bg,
    short* __restrict__ q_bf, short* __restrict__ k_bf,
    short* __restrict__ vT_bf, float* __restrict__ g_ws,
    float* __restrict__ ni)
{
    __shared__ char s_stage[4 * 8192];
    const int lane = threadIdx.x & 63;
    const int wid  = threadIdx.x >> 6;
    const int r    = lane & 15;
    const int c    = lane >> 4;

    if (blockIdx.x >= 128) {
        // ================= pair path =================
        const int wave = (blockIdx.x - 128) * 4 + wid;
        char* my = s_stage + wid * 8192;

        bf16x8 bfrag[4];
#pragma unroll
        for (int s = 0; s < 4; s++)
            bfrag[s] = *(const bf16x8*)(gwfB + (s * 64 + lane) * 8);
        const int n4 = r & 3;
        const float Al = AB[n4], Ag = AB[4 + n4];
        const float Bl = AB[8 + n4], Bg = AB[12 + n4];

        f32x4 ld[8];
        float pm0, pm1;

        pb_load_coal(ld, pm0, wave, pair, pmask, lane, r);
        pb_stage(my, ld, lane);

#pragma unroll
        for (int it = 0; it < PB_ITERS; it++) {
            const int t = wave + it * PB_WAVES;
            if (it + 1 < PB_ITERS)
                pb_load_coal(ld, pm1, t + PB_WAVES, pair, pmask, lane, r);
            pb_compute(my, pm0, t, bfrag, Al, Ag, Bl, Bg, bias_bf, lane, r, c);
            if (it + 1 < PB_ITERS) {
                pb_stage(my, ld, lane);
                pm0 = pm1;
            }
        }
    } else {
        // ================= projection path (inline LN) =================
        const int px = blockIdx.x;
        const int m  = px >> 5;                    // 0..3 : q,k,v,g
        const int i0 = (px & 31) * 64 + wid * 16;  // row in [0, B*I)
        const float* src = (m == 0 || m == 3) ? node_i : node_j;
        const float* gam = (m == 0 || m == 3) ? g_i : g_j;
        const float* bet = (m == 0 || m == 3) ? b_i : b_j;
        const short* wbase = wT + m * 65536 + c * 8;

        const float* arow = src + (size_t)(i0 + r) * C_ + c * 8;
        float sum = 0.0f, sq = 0.0f;
#pragma unroll
        for (int kk = 0; kk < 16; kk++) {
            const f32x4 a0 = *(const f32x4*)(arow + kk * 32);
            const f32x4 a1 = *(const f32x4*)(arow + kk * 32 + 4);
            sum += a0.x + a0.y + a0.z + a0.w + a1.x + a1.y + a1.z + a1.w;
            sq = fmaf(a0.x, a0.x, sq); sq = fmaf(a0.y, a0.y, sq);
            sq = fmaf(a0.z, a0.z, sq); sq = fmaf(a0.w, a0.w, sq);
            sq = fmaf(a1.x, a1.x, sq); sq = fmaf(a1.y, a1.y, sq);
            sq = fmaf(a1.z, a1.z, sq); sq = fmaf(a1.w, a1.w, sq);
        }
        sum += __shfl_xor(sum, 16); sum += __shfl_xor(sum, 32);
        sq  += __shfl_xor(sq, 16);  sq  += __shfl_xor(sq, 32);
        const float mean = sum * (1.0f / C_);
        const float rstd = rsqrtf(sq * (1.0f / C_) - mean * mean + EPS_);

        f32x4 acc[8];
#pragma unroll
        for (int nt = 0; nt < 8; nt++) acc[nt] = (f32x4){0.0f, 0.0f, 0.0f, 0.0f};

#pragma unroll 4
        for (int kk = 0; kk < 16; kk++) {
            const f32x4 a0 = *(const f32x4*)(arow + kk * 32);
            const f32x4 a1 = *(const f32x4*)(arow + kk * 32 + 4);
            const f32x4 ga0 = *(const f32x4*)(gam + c * 8 + kk * 32);
            const f32x4 ga1 = *(const f32x4*)(gam + c * 8 + kk * 32 + 4);
            const f32x4 be0 = *(const f32x4*)(bet + c * 8 + kk * 32);
            const f32x4 be1 = *(const f32x4*)(bet + c * 8 + kk * 32 + 4);
            f32x4 n0, n1;
            n0.x = fmaf((a0.x - mean) * rstd, ga0.x, be0.x);
            n0.y = fmaf((a0.y - mean) * rstd, ga0.y, be0.y);
            n0.z = fmaf((a0.z - mean) * rstd, ga0.z, be0.z);
            n0.w = fmaf((a0.w - mean) * rstd, ga0.w, be0.w);
            n1.x = fmaf((a1.x - mean) * rstd, ga1.x, be1.x);
            n1.y = fmaf((a1.y - mean) * rstd, ga1.y, be1.y);
            n1.z = fmaf((a1.z - mean) * rstd, ga1.z, be1.z);
            n1.w = fmaf((a1.w - mean) * rstd, ga1.w, be1.w);
            if (m == 0) {
                float* np = ni + (size_t)(i0 + r) * C_ + c * 8 + kk * 32;
                *(f32x4*)np       = n0;
                *(f32x4*)(np + 4) = n1;
            }
            bf16x8 af;
            af[0] = f2bf(n0.x); af[1] = f2bf(n0.y); af[2] = f2bf(n0.z); af[3] = f2bf(n0.w);
            af[4] = f2bf(n1.x); af[5] = f2bf(n1.y); af[6] = f2bf(n1.z); af[7] = f2bf(n1.w);
#pragma unroll
            for (int nt = 0; nt < 8; nt++) {
                const bf16x8 bf = *(const bf16x8*)(wbase + (nt * 16 + r) * 512 + kk * 32);
                acc[nt] = __builtin_amdgcn_mfma_f32_16x16x32_bf16(af, bf, acc[nt], 0, 0, 0);
            }
        }

        const int b  = i0 >> 9;
        const int il = i0 & 511;
#pragma unroll
        for (int nt = 0; nt < 8; nt++) {
            const int col = nt * 16 + r;
            if (m == 3) {
                const float bgc = bg[col];
#pragma unroll
                for (int reg = 0; reg < 4; reg++) {
                    const int row = i0 + c * 4 + reg;
                    g_ws[(size_t)row * HD_ + col] =
                        1.0f / (1.0f + __expf(-(acc[nt][reg] + bgc)));
                }
            } else if (m == 2) {
                const int h = col >> 5, d = col & 31;
                const int j = il + c * 4;
                s16x4 pk;
                pk[0] = f2bf(acc[nt][0]); pk[1] = f2bf(acc[nt][1]);
                pk[2] = f2bf(acc[nt][2]); pk[3] = f2bf(acc[nt][3]);
                *(s16x4*)(vT_bf + ((size_t)(b * H_ + h) * D_ + d) * J_ + j) = pk;
            } else {
                short* dst = (m == 0) ? q_bf : k_bf;
                const int h = col >> 5, d = col & 31;
#pragma unroll
                for (int reg = 0; reg < 4; reg++) {
                    const int i = il + c * 4 + reg;
                    dst[((size_t)(b * H_ + h) * 512 + i) * D_ + d] = f2bf(acc[nt][reg]);
                }
            }
        }
    }
}

// ---------------------------------------------------------------------------
// K3: fused attention + output projection + residual, 4-row i tiles.
// Block = (4-i rows, b), 8 waves; wave = (h = w>>1, jh = w&1).
// q rows duplicated r&3 -> all C rows are valid duplicates; writers c==0.
// grid: (I/4, B), block: 512
// ---------------------------------------------------------------------------
__global__ __launch_bounds__(512) void k_attn2(
    const short* __restrict__ q_bf, const short* __restrict__ k_bf,
    const short* __restrict__ vT_bf, const short* __restrict__ bias_bf,
    const float* __restrict__ g_ws, const short* __restrict__ woT,
    const float* __restrict__ ni, const float* __restrict__ bo,
    const int* __restrict__ nmask, float* __restrict__ out)
{
    __shared__ short s_p[28 * 520];     // 4 heads x 4 rows (pitch 520) + 12 overrun
    __shared__ short s_og[16 * 136];    // rows 4..15 pad for MFMA A reads
    __shared__ float s_red[64];         // [0:32) max, [32:64) sum

    const int tid  = threadIdx.x;
    const int w    = tid >> 6;
    const int lane = tid & 63;
    const int r    = lane & 15;
    const int c    = lane >> 4;
    const int b    = blockIdx.y;
    const int i0   = blockIdx.x * 4;

    const int h  = w >> 1;
    const int jh = w & 1;
    const size_t bhI = (size_t)(b * 4 + h) * 512;

    // ---- QK^T with bias C-init ----
    const bf16x8 qf = *(const bf16x8*)(q_bf + (bhI + i0 + (r & 3)) * 32 + c * 8);
    f32x4 acc[16];
#pragma unroll
    for (int t = 0; t < 16; t++) {
        const int jt = jh * 16 + t;
        const short* bp = bias_bf + (bhI + i0) * 512 + jt * 16 + r;
        f32x4 ci;
#pragma unroll
        for (int reg = 0; reg < 4; reg++)
            ci[reg] = bf2f(bp[(size_t)((c * 4 + reg) & 3) * 512]);
        const bf16x8 kf = *(const bf16x8*)(k_bf + (bhI + jt * 16 + r) * 32 + c * 8);
        acc[t] = __builtin_amdgcn_mfma_f32_16x16x32_bf16(qf, kf, ci, 0, 0, 0);
    }

    // ---- row max over this wave's 256 j ----
    float mx[4];
#pragma unroll
    for (int reg = 0; reg < 4; reg++) {
        float m0 = acc[0][reg];
#pragma unroll
        for (int t = 1; t < 16; t++) m0 = fmaxf(m0, acc[t][reg]);
        mx[reg] = m0;
    }
#pragma unroll
    for (int mm = 1; mm < 16; mm <<= 1) {
#pragma unroll
        for (int reg = 0; reg < 4; reg++)
            mx[reg] = fmaxf(mx[reg], __shfl_xor(mx[reg], mm));
    }
    if (r < 4 && c == 0) s_red[w * 4 + r] = mx[r];
    __syncthreads();

    float M[4];
#pragma unroll
    for (int reg = 0; reg < 4; reg++) {
        const int row = (c * 4 + reg) & 3;
        M[reg] = fmaxf(s_red[(2 * h) * 4 + row], s_red[(2 * h + 1) * 4 + row]);
    }

    // ---- P = exp(logit - M), bf16 LDS, sums ----
    float sm[4] = {0.0f, 0.0f, 0.0f, 0.0f};
#pragma unroll
    for (int t = 0; t < 16; t++) {
        const int j = jh * 256 + t * 16 + r;
#pragma unroll
        for (int reg = 0; reg < 4; reg++) {
            const float p = __expf(acc[t][reg] - M[reg]);
            sm[reg] += p;
            if (c == 0) s_p[h * 2080 + reg * 520 + j] = f2bf(p);
        }
    }
#pragma unroll
    for (int mm = 1; mm < 16; mm <<= 1) {
#pragma unroll
        for (int reg = 0; reg < 4; reg++)
            sm[reg] += __shfl_xor(sm[reg], mm);
    }
    if (r < 4 && c == 0) s_red[32 + w * 4 + r] = sm[r];
    __syncthreads();

    // ---- PV + gate ----
    {
        const int dt = jh;
        f32x4 oacc = {0.0f, 0.0f, 0.0f, 0.0f};
        const short* vrow = vT_bf + ((size_t)(b * 4 + h) * 32 + dt * 16 + r) * 512 + c * 8;
        const short* Pb = s_p + h * 2080 + r * 520 + c * 8;
#pragma unroll
        for (int kk = 0; kk < 16; kk++) {
            const bf16x8 pf = *(const bf16x8*)(Pb + kk * 32);
            const bf16x8 vf = *(const bf16x8*)(vrow + kk * 32);
            oacc = __builtin_amdgcn_mfma_f32_16x16x32_bf16(pf, vf, oacc, 0, 0, 0);
        }
        if (c == 0) {
            const int col = h * 32 + dt * 16 + r;
#pragma unroll
            for (int reg = 0; reg < 4; reg++) {
                const float den = s_red[32 + (2 * h) * 4 + reg]
                                + s_red[32 + (2 * h + 1) * 4 + reg];
                const float g = g_ws[((size_t)(b * 512 + i0 + reg)) * HD_ + col];
                s_og[reg * 136 + col] = f2bf(oacc[reg] / den * g);
            }
        }
    }
    __syncthreads();

    // ---- out GEMM + residual ----
    bf16x8 af[4];
#pragma unroll
    for (int ks = 0; ks < 4; ks++)
        af[ks] = *(const bf16x8*)(s_og + r * 136 + ks * 32 + c * 8);

#pragma unroll
    for (int ct = 0; ct < 4; ct++) {
        const int colt = w * 4 + ct;
        f32x4 oa = {0.0f, 0.0f, 0.0f, 0.0f};
#pragma unroll
        for (int ks = 0; ks < 4; ks++) {
            const bf16x8 bf = *(const bf16x8*)(woT + (colt * 16 + r) * HD_ + ks * 32 + c * 8);
            oa = __builtin_amdgcn_mfma_f32_16x16x32_bf16(af[ks], bf, oa, 0, 0, 0);
        }
        const int outc = colt * 16 + r;
        if (c == 0) {
            const float bov = bo[outc];
#pragma unroll
            for (int reg = 0; reg < 4; reg++) {
                const int row = b * 512 + i0 + reg;
                const float mk = (float)nmask[row];
                const size_t off = (size_t)row * C_ + outc;
                out[off] = ni[off] + (oa[reg] + bov) * mk;
            }
        }
    }
}

// ---------------------------------------------------------------------------
extern "C" void kernel_launch(void* const* d_in, const int* in_sizes, int n_in,
                              void* d_out, int out_size, void* d_ws, size_t ws_size,
                              hipStream_t stream)
{
    const float* node_i = (const float*)d_in[0];
    const float* node_j = (const float*)d_in[1];
    const float* pair   = (const float*)d_in[2];
    const int*   pmask  = (const int*)d_in[3];
    const int*   nmask  = (const int*)d_in[4];
    const float* ln_i_g = (const float*)d_in[5];
    const float* ln_i_b = (const float*)d_in[6];
    const float* ln_j_g = (const float*)d_in[7];
    const float* ln_j_b = (const float*)d_in[8];
    const float* ln_p_g = (const float*)d_in[9];
    const float* ln_p_b = (const float*)d_in[10];
    const float* w_pb   = (const float*)d_in[11];
    const float* w_pg   = (const float*)d_in[12];
    const float* wq     = (const float*)d_in[13];
    const float* wk     = (const float*)d_in[14];
    const float* wv     = (const float*)d_in[15];
    const float* wg     = (const float*)d_in[16];
    const float* bg     = (const float*)d_in[17];
    const float* wo     = (const float*)d_in[18];
    const float* bo     = (const float*)d_in[19];

    float* out = (float*)d_out;
    float* ws  = (float*)d_ws;

    float* ni      = ws;                       // 1,048,576 floats
    short* bias_bf = (short*)(ws + 1048576);   // 4,194,304 shorts (8 MB)
    float* g_ws    = ws + 3145728;             // 262,144 floats
    short* q_bf    = (short*)(ws + 3407872);   // 262,144 shorts
    short* k_bf    = (short*)(ws + 3538944);   // 262,144 shorts
    short* vT_bf   = (short*)(ws + 3670016);   // 262,144 shorts
    short* wT      = (short*)(ws + 3801088);   // 262,144 shorts
    short* gwfB    = (short*)(ws + 3932160);   // 2,048 shorts
    float* AB      = ws + 3933184;             // 16 floats
    short* woT     = (short*)(ws + 3933200);   // 65,536 shorts

    k_prep<<<dim3(161), 256, 0, stream>>>(ln_p_g, ln_p_b, w_pb, w_pg,
                                          wq, wk, wv, wg, wo,
                                          gwfB, AB, wT, woT);
    k_fused<<<dim3(128 + PB_BLOCKS), 256, 0, stream>>>(
        pair, pmask, gwfB, AB, bias_bf,
        node_i, node_j, ln_i_g, ln_i_b, ln_j_g, ln_j_b,
        wT, bg, q_bf, k_bf, vT_bf, g_ws, ni);
    k_attn2<<<dim3(128, 4), 512, 0, stream>>>(q_bf, k_bf, vT_bf, bias_bf,
                                              g_ws, woT, ni, bo, nmask, out);
}

// Round 12
// 139.627 us; speedup vs baseline: 1.0600x; 1.0600x over previous
//
#include <hip/hip_runtime.h>
#include <hip/hip_bf16.h>

#define B_ 4
#define I_ 512
#define J_ 512
#define C_ 512
#define P_ 128
#define H_ 4
#define D_ 32
#define HD_ 128
#define EPS_ 1e-5f
#define INF_ 1.0e9f
#define QSCALE_ 0.17677669529663689f

#define PB_BLOCKS 2048            // pair: persistent blocks (4 waves each)
#define PB_WAVES (PB_BLOCKS * 4)  // 8192 waves
#define PB_TILES 65536            // B*I*J/16
#define PB_ITERS (PB_TILES / PB_WAVES)  // 8 tiles per wave

typedef __attribute__((ext_vector_type(8))) short bf16x8;
typedef __attribute__((ext_vector_type(4))) short s16x4;
typedef __attribute__((ext_vector_type(4))) float f32x4;

__device__ __forceinline__ short f2bf(float f) {
    return __bfloat16_as_short(__float2bfloat16(f));
}
__device__ __forceinline__ float bf2f(short s) {
    return __uint_as_float(((unsigned)(unsigned short)s) << 16);
}

// ---------------------------------------------------------------------------
// K1: small prep.
//   block 0:         fold pair weights (MFMA B-frags) + AB[16]
//   blocks 1..128:   transpose {wq,wk,wv,wg} -> wT bf16 (q-scale folded)
//   blocks 129..160: transpose wo -> woT[col][k] bf16
// grid: 161 blocks, 256 threads
// ---------------------------------------------------------------------------
__global__ __launch_bounds__(256) void k_prep(
    const float* __restrict__ lng, const float* __restrict__ lnb,
    const float* __restrict__ wpb, const float* __restrict__ wpg,
    const float* __restrict__ wq, const float* __restrict__ wk,
    const float* __restrict__ wv, const float* __restrict__ wg,
    const float* __restrict__ wo,
    short* __restrict__ gwfB, float* __restrict__ AB,
    short* __restrict__ wT, short* __restrict__ woT)
{
    const int bx  = blockIdx.x;
    const int tid = threadIdx.x;

    if (bx == 0) {
        __shared__ float sAB[P_ * 16];
        const int s = tid >> 6, lane = tid & 63;
        const int c = lane >> 4, n = lane & 15;
#pragma unroll
        for (int e = 0; e < 8; e++) {
            const int p = s * 32 + c * 8 + e;
            const float w = (n < 4) ? wpb[p * 4 + n]
                          : (n < 8) ? wpg[p * 4 + (n - 4)] : 0.0f;
            gwfB[(s * 64 + lane) * 8 + e] = f2bf(lng[p] * w);
        }
        if (tid < P_) {
            const int p = tid;
            const float g = lng[p], b = lnb[p];
#pragma unroll
            for (int h = 0; h < 4; h++) {
                const float wb = wpb[p * 4 + h], wgv = wpg[p * 4 + h];
                sAB[p * 16 + h]      = g * wb;
                sAB[p * 16 + 4 + h]  = g * wgv;
                sAB[p * 16 + 8 + h]  = b * wb;
                sAB[p * 16 + 12 + h] = b * wgv;
            }
        }
        __syncthreads();
        if (tid < 16) {
            float a = 0.0f;
            for (int p = 0; p < P_; p++) a += sAB[p * 16 + tid];
            AB[tid] = a;
        }
    } else if (bx < 129) {
        const int bx2 = bx - 1;             // 0..127
        const int m   = bx2 >> 5, sub = bx2 & 31;
        const float* W = (m == 0) ? wq : (m == 1) ? wk : (m == 2) ? wv : wg;
        const float scale = (m == 0) ? QSCALE_ : 1.0f;
        const int col = sub * 4 + (tid >> 6);
        const int c0  = (tid & 63) * 8;
        bf16x8 pk;
#pragma unroll
        for (int u = 0; u < 8; u++)
            pk[u] = f2bf(W[(size_t)(c0 + u) * HD_ + col] * scale);
        *(bf16x8*)(wT + m * 65536 + col * 512 + c0) = pk;
    } else {
        const int bx3 = bx - 129;           // 0..31
        const int col = bx3 * 16 + (tid & 15);
        const int k0  = (tid >> 4) * 8;
        bf16x8 pk;
#pragma unroll
        for (int u = 0; u < 8; u++)
            pk[u] = f2bf(wo[(size_t)(k0 + u) * C_ + col]);
        *(bf16x8*)(woT + col * HD_ + k0) = pk;
    }
}

// ---------------------------------------------------------------------------
// pair helpers (NT loads; wave-private swizzled LDS bounce)
// ---------------------------------------------------------------------------
__device__ __forceinline__ void pb_load_coal(
    f32x4 (&ld)[8], float& pm, int tile,
    const float* __restrict__ pair, const int* __restrict__ pmask,
    int lane, int r)
{
    const float* tb = pair + (size_t)tile * 2048 + lane * 4;
#pragma unroll
    for (int s = 0; s < 8; s++)
        ld[s] = __builtin_nontemporal_load((const f32x4*)(tb + s * 256));
    pm = (float)pmask[tile * 16 + r];
}

__device__ __forceinline__ void pb_stage(
    char* __restrict__ my, const f32x4 (&ld)[8], int lane)
{
    const int half = lane >> 5;
    const int wb   = (lane & 31) * 16;
#pragma unroll
    for (int s = 0; s < 8; s++) {
        const int row = s * 2 + half;
        *(f32x4*)(my + row * 512 + (wb ^ ((row & 7) << 4))) = ld[s];
    }
}

__device__ __forceinline__ void pb_compute(
    const char* __restrict__ my, float pm, int tile,
    const bf16x8 (&bfrag)[4], float Al, float Ag, float Bl, float Bg,
    short* __restrict__ bias_bf, int lane, int r, int c)
{
    const char* rowb = my + r * 512;
    const int swz = (r & 7) << 4;
    f32x4 xa[4], xb[4];
#pragma unroll
    for (int ss = 0; ss < 4; ss++) {
        const int b0 = c * 32 + ss * 128;
        xa[ss] = *(const f32x4*)(rowb + ((b0)      ^ swz));
        xb[ss] = *(const f32x4*)(rowb + ((b0 + 16) ^ swz));
    }

    f32x4 acc = {0.0f, 0.0f, 0.0f, 0.0f};
    float sum = 0.0f, sq = 0.0f;
#pragma unroll
    for (int s = 0; s < 4; s++) {
        const float e0 = xa[s].x, e1 = xa[s].y, e2 = xa[s].z, e3 = xa[s].w;
        const float e4 = xb[s].x, e5 = xb[s].y, e6 = xb[s].z, e7 = xb[s].w;
        sum += e0 + e1 + e2 + e3 + e4 + e5 + e6 + e7;
        sq = fmaf(e0, e0, sq); sq = fmaf(e1, e1, sq);
        sq = fmaf(e2, e2, sq); sq = fmaf(e3, e3, sq);
        sq = fmaf(e4, e4, sq); sq = fmaf(e5, e5, sq);
        sq = fmaf(e6, e6, sq); sq = fmaf(e7, e7, sq);
        bf16x8 afrag;
        afrag[0] = f2bf(e0); afrag[1] = f2bf(e1);
        afrag[2] = f2bf(e2); afrag[3] = f2bf(e3);
        afrag[4] = f2bf(e4); afrag[5] = f2bf(e5);
        afrag[6] = f2bf(e6); afrag[7] = f2bf(e7);
        acc = __builtin_amdgcn_mfma_f32_16x16x32_bf16(afrag, bfrag[s], acc, 0, 0, 0);
    }

    sum += __shfl_xor(sum, 16); sum += __shfl_xor(sum, 32);
    sq  += __shfl_xor(sq, 16);  sq  += __shfl_xor(sq, 32);
    const float mean = sum * (1.0f / P_);
    const float rstd = rsqrtf(sq * (1.0f / P_) - mean * mean + EPS_);
    const float mr   = mean * rstd;
    const float mb   = INF_ * (pm - 1.0f);

    const int base = tile * 16;
    const int j0 = base & (J_ - 1);
    const int i  = (base >> 9) & (I_ - 1);
    const int b  = base >> 18;
    const int n4 = r & 3;
    short* obase = bias_bf + (((size_t)(b * H_ + n4) * I_ + i) << 9) + j0;

    s16x4 pk;
#pragma unroll
    for (int reg = 0; reg < 4; reg++) {
        const int rr = c * 4 + reg;
        const float rstd_r = __shfl(rstd, rr);
        const float mr_r   = __shfl(mr, rr);
        const float mb_r   = __shfl(mb, rr);
        const float Sg     = __shfl(acc[reg], lane + 4);
        const float left = fmaf(rstd_r, acc[reg], fmaf(-mr_r, Al, Bl));
        const float glog = fmaf(rstd_r, Sg,       fmaf(-mr_r, Ag, Bg));
        pk[reg] = f2bf(left * (1.0f / (1.0f + __expf(-glog))) + mb_r);
    }
    if (r < 4) *(s16x4*)(obase + c * 4) = pk;   // 4 contiguous j -> one 8B store
}

// ---------------------------------------------------------------------------
// K2: fused kernel.
//   blocks 0..127:   projections with inline LayerNorm (m==0 writes ni)
//   blocks 128..+PB: persistent pair-bias stream (NT, LDS bounce), bf16 bias
// grid: 128 + PB_BLOCKS, block: 256
// ---------------------------------------------------------------------------
__global__ __launch_bounds__(256, 4) void k_fused(
    const float* __restrict__ pair, const int* __restrict__ pmask,
    const short* __restrict__ gwfB, const float* __restrict__ AB,
    short* __restrict__ bias_bf,
    const float* __restrict__ node_i, const float* __restrict__ node_j,
    const float* __restrict__ g_i, const float* __restrict__ b_i,
    const float* __restrict__ g_j, const float* __restrict__ b_j,
    const short* __restrict__ wT, const float* __restrict__ bg,
    short* __restrict__ q_bf, short* __restrict__ k_bf,
    short* __restrict__ vT_bf, float* __restrict__ g_ws,
    float* __restrict__ ni)
{
    __shared__ char s_stage[4 * 8192];
    const int lane = threadIdx.x & 63;
    const int wid  = threadIdx.x >> 6;
    const int r    = lane & 15;
    const int c    = lane >> 4;

    if (blockIdx.x >= 128) {
        // ================= pair path =================
        const int wave = (blockIdx.x - 128) * 4 + wid;
        char* my = s_stage + wid * 8192;

        bf16x8 bfrag[4];
#pragma unroll
        for (int s = 0; s < 4; s++)
            bfrag[s] = *(const bf16x8*)(gwfB + (s * 64 + lane) * 8);
        const int n4 = r & 3;
        const float Al = AB[n4], Ag = AB[4 + n4];
        const float Bl = AB[8 + n4], Bg = AB[12 + n4];

        f32x4 ld[8];
        float pm0, pm1;

        pb_load_coal(ld, pm0, wave, pair, pmask, lane, r);
        pb_stage(my, ld, lane);

#pragma unroll
        for (int it = 0; it < PB_ITERS; it++) {
            const int t = wave + it * PB_WAVES;
            if (it + 1 < PB_ITERS)
                pb_load_coal(ld, pm1, t + PB_WAVES, pair, pmask, lane, r);
            pb_compute(my, pm0, t, bfrag, Al, Ag, Bl, Bg, bias_bf, lane, r, c);
            if (it + 1 < PB_ITERS) {
                pb_stage(my, ld, lane);
                pm0 = pm1;
            }
        }
    } else {
        // ================= projection path (inline LN) =================
        const int px = blockIdx.x;
        const int m  = px >> 5;                    // 0..3 : q,k,v,g
        const int i0 = (px & 31) * 64 + wid * 16;  // row in [0, B*I)
        const float* src = (m == 0 || m == 3) ? node_i : node_j;
        const float* gam = (m == 0 || m == 3) ? g_i : g_j;
        const float* bet = (m == 0 || m == 3) ? b_i : b_j;
        const short* wbase = wT + m * 65536 + c * 8;

        const float* arow = src + (size_t)(i0 + r) * C_ + c * 8;
        float sum = 0.0f, sq = 0.0f;
#pragma unroll
        for (int kk = 0; kk < 16; kk++) {
            const f32x4 a0 = *(const f32x4*)(arow + kk * 32);
            const f32x4 a1 = *(const f32x4*)(arow + kk * 32 + 4);
            sum += a0.x + a0.y + a0.z + a0.w + a1.x + a1.y + a1.z + a1.w;
            sq = fmaf(a0.x, a0.x, sq); sq = fmaf(a0.y, a0.y, sq);
            sq = fmaf(a0.z, a0.z, sq); sq = fmaf(a0.w, a0.w, sq);
            sq = fmaf(a1.x, a1.x, sq); sq = fmaf(a1.y, a1.y, sq);
            sq = fmaf(a1.z, a1.z, sq); sq = fmaf(a1.w, a1.w, sq);
        }
        sum += __shfl_xor(sum, 16); sum += __shfl_xor(sum, 32);
        sq  += __shfl_xor(sq, 16);  sq  += __shfl_xor(sq, 32);
        const float mean = sum * (1.0f / C_);
        const float rstd = rsqrtf(sq * (1.0f / C_) - mean * mean + EPS_);

        f32x4 acc[8];
#pragma unroll
        for (int nt = 0; nt < 8; nt++) acc[nt] = (f32x4){0.0f, 0.0f, 0.0f, 0.0f};

#pragma unroll 4
        for (int kk = 0; kk < 16; kk++) {
            const f32x4 a0 = *(const f32x4*)(arow + kk * 32);
            const f32x4 a1 = *(const f32x4*)(arow + kk * 32 + 4);
            const f32x4 ga0 = *(const f32x4*)(gam + c * 8 + kk * 32);
            const f32x4 ga1 = *(const f32x4*)(gam + c * 8 + kk * 32 + 4);
            const f32x4 be0 = *(const f32x4*)(bet + c * 8 + kk * 32);
            const f32x4 be1 = *(const f32x4*)(bet + c * 8 + kk * 32 + 4);
            f32x4 n0, n1;
            n0.x = fmaf((a0.x - mean) * rstd, ga0.x, be0.x);
            n0.y = fmaf((a0.y - mean) * rstd, ga0.y, be0.y);
            n0.z = fmaf((a0.z - mean) * rstd, ga0.z, be0.z);
            n0.w = fmaf((a0.w - mean) * rstd, ga0.w, be0.w);
            n1.x = fmaf((a1.x - mean) * rstd, ga1.x, be1.x);
            n1.y = fmaf((a1.y - mean) * rstd, ga1.y, be1.y);
            n1.z = fmaf((a1.z - mean) * rstd, ga1.z, be1.z);
            n1.w = fmaf((a1.w - mean) * rstd, ga1.w, be1.w);
            if (m == 0) {
                float* np = ni + (size_t)(i0 + r) * C_ + c * 8 + kk * 32;
                *(f32x4*)np       = n0;
                *(f32x4*)(np + 4) = n1;
            }
            bf16x8 af;
            af[0] = f2bf(n0.x); af[1] = f2bf(n0.y); af[2] = f2bf(n0.z); af[3] = f2bf(n0.w);
            af[4] = f2bf(n1.x); af[5] = f2bf(n1.y); af[6] = f2bf(n1.z); af[7] = f2bf(n1.w);
#pragma unroll
            for (int nt = 0; nt < 8; nt++) {
                const bf16x8 bf = *(const bf16x8*)(wbase + (nt * 16 + r) * 512 + kk * 32);
                acc[nt] = __builtin_amdgcn_mfma_f32_16x16x32_bf16(af, bf, acc[nt], 0, 0, 0);
            }
        }

        const int b  = i0 >> 9;
        const int il = i0 & 511;
#pragma unroll
        for (int nt = 0; nt < 8; nt++) {
            const int col = nt * 16 + r;
            if (m == 3) {
                const float bgc = bg[col];
#pragma unroll
                for (int reg = 0; reg < 4; reg++) {
                    const int row = i0 + c * 4 + reg;
                    g_ws[(size_t)row * HD_ + col] =
                        1.0f / (1.0f + __expf(-(acc[nt][reg] + bgc)));
                }
            } else if (m == 2) {
                const int h = col >> 5, d = col & 31;
                const int j = il + c * 4;
                s16x4 pk;
                pk[0] = f2bf(acc[nt][0]); pk[1] = f2bf(acc[nt][1]);
                pk[2] = f2bf(acc[nt][2]); pk[3] = f2bf(acc[nt][3]);
                *(s16x4*)(vT_bf + ((size_t)(b * H_ + h) * D_ + d) * J_ + j) = pk;
            } else {
                short* dst = (m == 0) ? q_bf : k_bf;
                const int h = col >> 5, d = col & 31;
#pragma unroll
                for (int reg = 0; reg < 4; reg++) {
                    const int i = il + c * 4 + reg;
                    dst[((size_t)(b * H_ + h) * 512 + i) * D_ + d] = f2bf(acc[nt][reg]);
                }
            }
        }
    }
}

// ---------------------------------------------------------------------------
// K3: fused attention + output projection + residual, 8-row i tiles
// (verified R10 structure; bias bf16).
// Block = (8-i rows, b), 8 waves; wave = (h = w>>1, jh = w&1).
// grid: (I/8, B), block: 512
// ---------------------------------------------------------------------------
__global__ __launch_bounds__(512) void k_attn2(
    const short* __restrict__ q_bf, const short* __restrict__ k_bf,
    const short* __restrict__ vT_bf, const short* __restrict__ bias_bf,
    const float* __restrict__ g_ws, const short* __restrict__ woT,
    const float* __restrict__ ni, const float* __restrict__ bo,
    const int* __restrict__ nmask, float* __restrict__ out)
{
    __shared__ short s_p[40 * 520];
    __shared__ short s_og[16 * 136];
    __shared__ float s_red[128];

    const int tid  = threadIdx.x;
    const int w    = tid >> 6;
    const int lane = tid & 63;
    const int r    = lane & 15;
    const int c    = lane >> 4;
    const int b    = blockIdx.y;
    const int i0   = blockIdx.x * 8;

    const int h  = w >> 1;
    const int jh = w & 1;
    const size_t bhI = (size_t)(b * 4 + h) * 512;

    // ---- QK^T with bias C-init ----
    const bf16x8 qf = *(const bf16x8*)(q_bf + (bhI + i0 + (r & 7)) * 32 + c * 8);
    f32x4 acc[16];
#pragma unroll
    for (int t = 0; t < 16; t++) {
        const int jt = jh * 16 + t;
        const short* bp = bias_bf + (bhI + i0) * 512 + jt * 16 + r;
        f32x4 ci;
#pragma unroll
        for (int reg = 0; reg < 4; reg++)
            ci[reg] = bf2f(bp[(size_t)((c * 4 + reg) & 7) * 512]);
        const bf16x8 kf = *(const bf16x8*)(k_bf + (bhI + jt * 16 + r) * 32 + c * 8);
        acc[t] = __builtin_amdgcn_mfma_f32_16x16x32_bf16(qf, kf, ci, 0, 0, 0);
    }

    // ---- row max ----
    float mx[4];
#pragma unroll
    for (int reg = 0; reg < 4; reg++) {
        float m0 = acc[0][reg];
#pragma unroll
        for (int t = 1; t < 16; t++) m0 = fmaxf(m0, acc[t][reg]);
        mx[reg] = m0;
    }
#pragma unroll
    for (int mm = 1; mm < 16; mm <<= 1) {
#pragma unroll
        for (int reg = 0; reg < 4; reg++)
            mx[reg] = fmaxf(mx[reg], __shfl_xor(mx[reg], mm));
    }
    if (r < 4 && c < 2) s_red[w * 8 + c * 4 + r] = mx[r];
    __syncthreads();

    float M[4];
#pragma unroll
    for (int reg = 0; reg < 4; reg++) {
        const int row = (c * 4 + reg) & 7;
        M[reg] = fmaxf(s_red[(2 * h) * 8 + row], s_red[(2 * h + 1) * 8 + row]);
    }

    // ---- P = exp(logit - M) ----
    float sm[4] = {0.0f, 0.0f, 0.0f, 0.0f};
#pragma unroll
    for (int t = 0; t < 16; t++) {
        const int j = jh * 256 + t * 16 + r;
#pragma unroll
        for (int reg = 0; reg < 4; reg++) {
            const float p = __expf(acc[t][reg] - M[reg]);
            sm[reg] += p;
            if (c < 2) s_p[h * 4160 + (c * 4 + reg) * 520 + j] = f2bf(p);
        }
    }
#pragma unroll
    for (int mm = 1; mm < 16; mm <<= 1) {
#pragma unroll
        for (int reg = 0; reg < 4; reg++)
            sm[reg] += __shfl_xor(sm[reg], mm);
    }
    if (r < 4 && c < 2) s_red[64 + w * 8 + c * 4 + r] = sm[r];
    __syncthreads();

    // ---- PV + gate ----
    {
        const int dt = jh;
        f32x4 oacc = {0.0f, 0.0f, 0.0f, 0.0f};
        const short* vrow = vT_bf + ((size_t)(b * 4 + h) * 32 + dt * 16 + r) * 512 + c * 8;
        const short* Pb = s_p + h * 4160 + r * 520 + c * 8;
#pragma unroll
        for (int kk = 0; kk < 16; kk++) {
            const bf16x8 pf = *(const bf16x8*)(Pb + kk * 32);
            const bf16x8 vf = *(const bf16x8*)(vrow + kk * 32);
            oacc = __builtin_amdgcn_mfma_f32_16x16x32_bf16(pf, vf, oacc, 0, 0, 0);
        }
        if (c < 2) {
            const int col = h * 32 + dt * 16 + r;
#pragma unroll
            for (int reg = 0; reg < 4; reg++) {
                const int i = c * 4 + reg;
                const float den = s_red[64 + (2 * h) * 8 + i]
                                + s_red[64 + (2 * h + 1) * 8 + i];
                const float g = g_ws[((size_t)(b * 512 + i0 + i)) * HD_ + col];
                s_og[i * 136 + col] = f2bf(oacc[reg] / den * g);
            }
        }
    }
    __syncthreads();

    // ---- out GEMM + residual ----
    bf16x8 af[4];
#pragma unroll
    for (int ks = 0; ks < 4; ks++)
        af[ks] = *(const bf16x8*)(s_og + r * 136 + ks * 32 + c * 8);

#pragma unroll
    for (int ct = 0; ct < 4; ct++) {
        const int colt = w * 4 + ct;
        f32x4 oa = {0.0f, 0.0f, 0.0f, 0.0f};
#pragma unroll
        for (int ks = 0; ks < 4; ks++) {
            const bf16x8 bf = *(const bf16x8*)(woT + (colt * 16 + r) * HD_ + ks * 32 + c * 8);
            oa = __builtin_amdgcn_mfma_f32_16x16x32_bf16(af[ks], bf, oa, 0, 0, 0);
        }
        const int outc = colt * 16 + r;
        if (c < 2) {
            const float bov = bo[outc];
#pragma unroll
            for (int reg = 0; reg < 4; reg++) {
                const int row = b * 512 + i0 + c * 4 + reg;
                const float mk = (float)nmask[row];
                const size_t off = (size_t)row * C_ + outc;
                out[off] = ni[off] + (oa[reg] + bov) * mk;
            }
        }
    }
}

// ---------------------------------------------------------------------------
extern "C" void kernel_launch(void* const* d_in, const int* in_sizes, int n_in,
                              void* d_out, int out_size, void* d_ws, size_t ws_size,
                              hipStream_t stream)
{
    const float* node_i = (const float*)d_in[0];
    const float* node_j = (const float*)d_in[1];
    const float* pair   = (const float*)d_in[2];
    const int*   pmask  = (const int*)d_in[3];
    const int*   nmask  = (const int*)d_in[4];
    const float* ln_i_g = (const float*)d_in[5];
    const float* ln_i_b = (const float*)d_in[6];
    const float* ln_j_g = (const float*)d_in[7];
    const float* ln_j_b = (const float*)d_in[8];
    const float* ln_p_g = (const float*)d_in[9];
    const float* ln_p_b = (const float*)d_in[10];
    const float* w_pb   = (const float*)d_in[11];
    const float* w_pg   = (const float*)d_in[12];
    const float* wq     = (const float*)d_in[13];
    const float* wk     = (const float*)d_in[14];
    const float* wv     = (const float*)d_in[15];
    const float* wg     = (const float*)d_in[16];
    const float* bg     = (const float*)d_in[17];
    const float* wo     = (const float*)d_in[18];
    const float* bo     = (const float*)d_in[19];

    float* out = (float*)d_out;
    float* ws  = (float*)d_ws;

    float* ni      = ws;                       // 1,048,576 floats
    short* bias_bf = (short*)(ws + 1048576);   // 4,194,304 shorts (8 MB)
    float* g_ws    = ws + 3145728;             // 262,144 floats
    short* q_bf    = (short*)(ws + 3407872);   // 262,144 shorts
    short* k_bf    = (short*)(ws + 3538944);   // 262,144 shorts
    short* vT_bf   = (short*)(ws + 3670016);   // 262,144 shorts
    short* wT      = (short*)(ws + 3801088);   // 262,144 shorts
    short* gwfB    = (short*)(ws + 3932160);   // 2,048 shorts
    float* AB      = ws + 3933184;             // 16 floats
    short* woT     = (short*)(ws + 3933200);   // 65,536 shorts

    k_prep<<<dim3(161), 256, 0, stream>>>(ln_p_g, ln_p_b, w_pb, w_pg,
                                          wq, wk, wv, wg, wo,
                                          gwfB, AB, wT, woT);
    k_fused<<<dim3(128 + PB_BLOCKS), 256, 0, stream>>>(
        pair, pmask, gwfB, AB, bias_bf,
        node_i, node_j, ln_i_g, ln_i_b, ln_j_g, ln_j_b,
        wT, bg, q_bf, k_bf, vT_bf, g_ws, ni);
    k_attn2<<<dim3(64, 4), 512, 0, stream>>>(q_bf, k_bf, vT_bf, bias_bf,
                                             g_ws, woT, ni, bo, nmask, out);
}